// Round 10
// baseline (1844.689 us; speedup 1.0000x reference)
//
#include <hip/hip_runtime.h>

// CTC loss (blank=0, mean reduction, zero_infinity) for
// B=64, T=1024, K=512, L=100  ->  S = 2L+1 = 201 extended states.
//
// FUSED producer/consumer pipeline (round 10):
//   grid = 64 consumer blocks + 16384 producer blocks, 256 threads each.
//   Producers (4 waves, 1 logit row each): softmax over K=512, emit 100
//     target ratios r = p_lab/p_blank into glp row (104 floats) and
//     lb = log2(512*p_blank) into lbArr; then fence(release, agent) +
//     atomicAdd on cnt[b][chunk]. Production order alternates from both
//     ends (tgrp 0, 255, 1, 254, ...) so fwd AND bwd consumers are fed.
//   Consumers (block b < 64): the round-9-verified meet-in-the-middle
//     recursion. Wave 0 = forward rows 0..511, wave 1 = backward rows
//     1023..512 (lane-reversed so both use wave_shr:1 DPP). Per-lane
//     power-of-2 rescale every 4 steps (per-lane integer exponents;
//     round-8 lesson: wave-level normalization flushes saddle states).
//     Before each chunk's register-prefetch ISSUE: lane-0 relaxed spin on
//     cnt + acquire fence. 3-buffer ping-pong, 2-chunk slack.
//   Deadlock-free: 64 spinning blocks occupy <= 64 CUs; producers get the
//   other 192+. Flags zeroed per launch via hipMemsetAsync (capturable).
//   Combine: per state log2(A)+eaF+log2(G)+eaB -> wave logsumexp;
//   logl/ln2 = lse + sum_t lb(t) - T*9.

#define TT 1024
#define BB 64
#define KK 512
#define LL 100
#define ROW 104
#define CH 16                 // rows per chunk
#define NPROD 16384           // producer blocks (1 tgrp = 4 rows each)

static constexpr float L2E = 1.44269504088896340736f;
static constexpr float LN2 = 0.69314718055994530942f;

// lane i <- lane i-1, lane 0 <- 0.0f  (DPP wave_shr:1, VALU pipe)
__device__ __forceinline__ float dpp_shr1_z(float x) {
  return __builtin_bit_cast(float,
      __builtin_amdgcn_update_dpp(0, __builtin_bit_cast(int, x),
                                  0x138, 0xf, 0xf, true));
}

__device__ __forceinline__ float slog2(float x) {
  return x > 0.0f ? log2f(x) : -1.0e30f;
}

__global__ __launch_bounds__(256) void k_fused(const float* __restrict__ logits,
                                               const int* __restrict__ targets,
                                               float* __restrict__ glp,
                                               float* __restrict__ lbArr,
                                               int* __restrict__ cnt,
                                               float* __restrict__ per) {
  const int lane = threadIdx.x & 63;
  const int wv = threadIdx.x >> 6;

  __shared__ float sx[4][KK];                   // producer scratch
  __shared__ float sG[6][64];                   // consumer exchange

  if (blockIdx.x >= BB) {
    // ============================ producer ============================
    const int p = blockIdx.x - BB;
    const int g = p >> 6;                       // 0..255
    const int b = p & 63;
    const int tgrp = (g & 1) ? (255 - (g >> 1)) : (g >> 1);
    const int t = (tgrp << 2) + wv;             // this wave's row
    const int row = (b << 10) + t;
    const float* x = logits + (size_t)row * KK;

    const float4 v0 = reinterpret_cast<const float4*>(x)[lane];
    const float4 v1 = reinterpret_cast<const float4*>(x)[lane + 64];
    float4* sp = reinterpret_cast<float4*>(sx[wv]);
    sp[lane] = v0;
    sp[lane + 64] = v1;

    float m = fmaxf(fmaxf(fmaxf(v0.x, v0.y), fmaxf(v0.z, v0.w)),
                    fmaxf(fmaxf(v1.x, v1.y), fmaxf(v1.z, v1.w)));
    #pragma unroll
    for (int d = 1; d < 64; d <<= 1) m = fmaxf(m, __shfl_xor(m, d));

    float e = exp2f((v0.x - m) * L2E) + exp2f((v0.y - m) * L2E) +
              exp2f((v0.z - m) * L2E) + exp2f((v0.w - m) * L2E) +
              exp2f((v1.x - m) * L2E) + exp2f((v1.y - m) * L2E) +
              exp2f((v1.z - m) * L2E) + exp2f((v1.w - m) * L2E);
    #pragma unroll
    for (int d = 1; d < 64; d <<= 1) e += __shfl_xor(e, d);

    // blank logit = lane 0's v0.x
    const float xb = __builtin_bit_cast(float,
        __builtin_amdgcn_readlane(__builtin_bit_cast(int, v0.x), 0));

    if (lane < 52) {
      float2 o = {0.0f, 0.0f};
      if (lane >= 1 && lane <= 50) {
        const int2 c = *reinterpret_cast<const int2*>(
            targets + b * LL + (2 * lane - 2));
        o.x = exp2f((sx[wv][c.x] - xb) * L2E); // ratio p_lab / p_blank
        o.y = exp2f((sx[wv][c.y] - xb) * L2E);
      }
      reinterpret_cast<float2*>(glp + (size_t)row * ROW)[lane] = o;
    }
    if (lane == 0) lbArr[row] = (xb - m) * L2E + 9.0f - log2f(e);

    __builtin_amdgcn_fence(__ATOMIC_RELEASE, "agent");
    if (lane == 0)
      __hip_atomic_fetch_add(cnt + (b << 6) + (t >> 4), 1,
                             __ATOMIC_RELAXED, __HIP_MEMORY_SCOPE_AGENT);
    return;
  }

  // ============================ consumer ============================
  const int b = blockIdx.x;
  if (wv >= 2) { __syncthreads(); return; }     // waves 2,3: join barrier

  const int* tg = targets + b * LL;
  float a0 = 0.0f, a1 = 0.0f, a2 = 0.0f, a3 = 0.0f;
  float ea = 0.0f, f1 = 1.0f, f2 = 1.0f;
  float s4 = 0.0f;

  // spin until chunk CIDX fully produced (16 row-waves), then acquire.
#define WAITC(CIDX)                                                        \
  do {                                                                     \
    if (lane == 0) {                                                       \
      while (__hip_atomic_load(cnt + (b << 6) + (CIDX), __ATOMIC_RELAXED,  \
                               __HIP_MEMORY_SCOPE_AGENT) < 16)             \
        __builtin_amdgcn_s_sleep(1);                                       \
    }                                                                      \
    __builtin_amdgcn_fence(__ATOMIC_ACQUIRE, "agent");                     \
  } while (0)

#define PLRESCALE()                                                        \
  do {                                                                     \
    const float m_ = fmaxf(fmaxf(a0, a1), fmaxf(a2, a3));                  \
    int E_ = (int)((__float_as_uint(m_) >> 23) & 255) - 127;               \
    E_ = (m_ > 0.0f) ? E_ : 0;                                             \
    const float sc_ = __uint_as_float((unsigned)(127 - E_) << 23);         \
    a0 *= sc_; a1 *= sc_; a2 *= sc_; a3 *= sc_;                            \
    ea += (float)E_;                                                       \
    const float ep_ = dpp_shr1_z(ea);                                      \
    const float dE_ = fminf(fmaxf(ep_ - ea, -250.0f), 250.0f);             \
    const float h_ = truncf(dE_ * 0.5f);                                   \
    f1 = exp2f(h_); f2 = exp2f(dE_ - h_);                                  \
  } while (0)

  if (wv == 0) {
    // ------------- forward: rows 0..511, lane i = states 4i..4i+3 -------
    const int i = lane;
    int offlab = 2 + 2 * i;
    if (offlab > 102) offlab = 102;
    const float* gbase = glp + (size_t)b * TT * ROW + offlab;

    float mA = 0.0f, mB = 0.0f;
    if (i > 0 && 2 * i <= LL - 1) mA = (tg[2 * i] != tg[2 * i - 1]) ? 1.0f : 0.0f;
    if (2 * i + 1 <= LL - 1)      mB = (tg[2 * i + 1] != tg[2 * i]) ? 1.0f : 0.0f;
    a0 = (i == 0) ? 1.0f : 0.0f;                // virtual delta init

    float2 FA[16], FB[16], FC[16];
#define FISSUE(BUF, CHN)                                                   \
    do {                                                                   \
      _Pragma("unroll") for (int j = 0; j < 16; ++j)                       \
        BUF[j] = *reinterpret_cast<const float2*>(                         \
            gbase + (size_t)((CHN) * CH + j) * ROW);                       \
      __builtin_amdgcn_sched_barrier(0);                                   \
    } while (0)
#define FCOMPUTE(BUF)                                                      \
    do {                                                                   \
      _Pragma("unroll") for (int j = 0; j < 16; ++j) {                     \
        const float rx = BUF[j].x, ry = BUF[j].y;                          \
        const float A3 = dpp_shr1_z(a3) * f1 * f2;                         \
        const float n0 = a0 + A3;                                          \
        const float n1 = (a0 + a1 + mA * A3) * rx;                         \
        const float n2 = a1 + a2;                                          \
        const float n3 = (a2 + a3 + mB * a1) * ry;                         \
        a0 = n0; a1 = n1; a2 = n2; a3 = n3;                                \
        if ((j & 3) == 3) PLRESCALE();                                     \
      }                                                                    \
    } while (0)

    WAITC(0); FISSUE(FA, 0);
    WAITC(1); FISSUE(FB, 1);
    for (int c = 0; c < 30; c += 3) {
      WAITC(c + 2); FISSUE(FC, c + 2); FCOMPUTE(FA);
      WAITC(c + 3); FISSUE(FA, c + 3); FCOMPUTE(FB);
      WAITC(c + 4); FISSUE(FB, c + 4); FCOMPUTE(FC);
    }
    FCOMPUTE(FA);                               // chunk 30
    FCOMPUTE(FB);                               // chunk 31
#undef FISSUE
#undef FCOMPUTE

    // lb partial: rows 0..511 (acquired by this wave's chunk flags)
    const float4* lbv = reinterpret_cast<const float4*>(lbArr + (size_t)b * TT);
    #pragma unroll
    for (int j = 0; j < 2; ++j) {
      const float4 v = lbv[i + 64 * j];
      s4 += (v.x + v.y) + (v.z + v.w);
    }
    #pragma unroll
    for (int d = 1; d < 64; d <<= 1) s4 += __shfl_xor(s4, d);
  } else {
    // ------ backward: rows 1023..512, lane j = states of i' = 50-j ------
    const int ii = 50 - lane;
    int offlab = 2 + 2 * ii;
    if (offlab < 0) offlab = 0;
    const float* gbase = glp + (size_t)b * TT * ROW + offlab;

    float mB = 0.0f, mAn = 0.0f;
    if (ii >= 0 && 2 * ii + 1 <= LL - 1)
      mB = (tg[2 * ii + 1] != tg[2 * ii]) ? 1.0f : 0.0f;
    if (ii >= 0 && ii <= 48)
      mAn = (tg[2 * ii + 2] != tg[2 * ii + 1]) ? 1.0f : 0.0f;
    if (lane == 1) a3 = 1.0f;                   // state 199 (ii = 49)
    if (lane == 0) a0 = 1.0f;                   // state 200 (ii = 50)

    float2 GA[16], GB[16], GC[16];
#define BISSUE(BUF, CHN)                                                   \
    do {                                                                   \
      _Pragma("unroll") for (int j = 0; j < 16; ++j)                       \
        BUF[j] = *reinterpret_cast<const float2*>(                         \
            gbase + (size_t)(1023 - ((CHN) * CH + j)) * ROW);              \
      __builtin_amdgcn_sched_barrier(0);                                   \
    } while (0)
    // r2 (= row[offlab+2]) is the lane-(j-1) neighbor's r0: get via DPP.
#define BCOMPUTE(BUF)                                                      \
    do {                                                                   \
      _Pragma("unroll") for (int j = 0; j < 16; ++j) {                     \
        const float r0 = BUF[j].x, r1 = BUF[j].y;                          \
        const float r2 = dpp_shr1_z(r0);                                   \
        const float G0 = dpp_shr1_z(a0) * f1 * f2;                         \
        const float G1 = dpp_shr1_z(a1) * f1 * f2;                         \
        const float u = r0 * a1;                                           \
        const float v = r1 * a3;                                           \
        const float n0 = a0 + u;                                           \
        const float n1 = u + fmaf(mB, v, a2);                              \
        const float n2 = a2 + v;                                           \
        const float n3 = v + fmaf(mAn, r2 * G1, G0);                       \
        a0 = n0; a1 = n1; a2 = n2; a3 = n3;                                \
        if ((j & 3) == 3) PLRESCALE();                                     \
      }                                                                    \
    } while (0)

    WAITC(63); BISSUE(GA, 0);
    WAITC(62); BISSUE(GB, 1);
    for (int c = 0; c < 30; c += 3) {
      WAITC(61 - c); BISSUE(GC, c + 2); BCOMPUTE(GA);
      WAITC(60 - c); BISSUE(GA, c + 3); BCOMPUTE(GB);
      WAITC(59 - c); BISSUE(GB, c + 4); BCOMPUTE(GC);
    }
    BCOMPUTE(GA);                               // chunk 30 (rows 543..528)
    BCOMPUTE(GB);                               // chunk 31 (rows 527..512)
#undef BISSUE
#undef BCOMPUTE

    sG[0][lane] = a0; sG[1][lane] = a1; sG[2][lane] = a2; sG[3][lane] = a3;
    sG[4][lane] = ea;

    // lb partial: rows 512..1023 (acquired by this wave's chunk flags)
    const float4* lbv = reinterpret_cast<const float4*>(lbArr + (size_t)b * TT);
    #pragma unroll
    for (int j = 0; j < 2; ++j) {
      const float4 v = lbv[128 + lane + 64 * j];
      s4 += (v.x + v.y) + (v.z + v.w);
    }
    #pragma unroll
    for (int d = 1; d < 64; d <<= 1) s4 += __shfl_xor(s4, d);
    if (lane == 0) sG[5][0] = s4;
  }
#undef WAITC
#undef PLRESCALE

  __syncthreads();                              // backward publishes sG

  if (wv == 0) {
    const int i = lane;
    const int gj = (i <= 50) ? (50 - i) : 63;   // bwd lane holding states 4i..
    const float eb = sG[4][gj];
    float w0 = slog2(a0) + ea + slog2(sG[0][gj]) + eb;
    float w1 = slog2(a1) + ea + slog2(sG[1][gj]) + eb;
    float w2 = slog2(a2) + ea + slog2(sG[2][gj]) + eb;
    float w3 = slog2(a3) + ea + slog2(sG[3][gj]) + eb;
    float wm = fmaxf(fmaxf(w0, w1), fmaxf(w2, w3));
    #pragma unroll
    for (int d = 1; d < 64; d <<= 1) wm = fmaxf(wm, __shfl_xor(wm, d));
    float ss = exp2f(w0 - wm) + exp2f(w1 - wm) +
               exp2f(w2 - wm) + exp2f(w3 - wm);
    #pragma unroll
    for (int d = 1; d < 64; d <<= 1) ss += __shfl_xor(ss, d);

    if (i == 0) {
      const float lbsum = s4 + sG[5][0];        // fwd + bwd halves
      float loss = 0.0f;                        // zero_infinity
      if (wm > -1.0e29f) {
        const float logl2 = wm + log2f(ss) + lbsum - (float)(TT * 9);
        loss = -(logl2 * LN2) / (float)LL;
      }
      per[b] = loss;
    }
  }
}

__global__ __launch_bounds__(64) void k_mean(const float* __restrict__ per,
                                             float* __restrict__ out) {
  const int i = threadIdx.x;
  float v = per[i];
  #pragma unroll
  for (int d = 1; d < 64; d <<= 1) v += __shfl_xor(v, d);
  if (i == 0) out[0] = v * (1.0f / (float)BB);
}

extern "C" void kernel_launch(void* const* d_in, const int* in_sizes, int n_in,
                              void* d_out, int out_size, void* d_ws, size_t ws_size,
                              hipStream_t stream) {
  const float* logits = (const float*)d_in[0];   // (64, 1024, 512) f32
  const int* targets = (const int*)d_in[1];      // (64, 100) i32
  float* out = (float*)d_out;                    // scalar f32

  int* cnt = (int*)d_ws;                         // 64*64 chunk counters
  float* per = (float*)d_ws + 4096;              // 64
  float* glp = (float*)d_ws + 4160;              // 64*1024*104 (16B aligned)
  float* lbArr = glp + (size_t)BB * TT * ROW;    // 64*1024

  hipMemsetAsync(cnt, 0, 4096 * sizeof(int), stream);
  hipLaunchKernelGGL(k_fused, dim3(BB + NPROD), dim3(256), 0, stream,
                     logits, targets, glp, lbArr, cnt, per);
  hipLaunchKernelGGL(k_mean, dim3(1), dim3(64), 0, stream, per, out);
}

// Round 12
// 80.962 us; speedup vs baseline: 22.7847x; 22.7847x over previous
//
#include <hip/hip_runtime.h>

// CTC loss (blank=0, mean reduction, zero_infinity) for
// B=64, T=1024, K=512, L=100  ->  S = 2L+1 = 201 extended states.
//
// Ratio formulation: factor prod_t p_blank(t) out of all alpha states.
//   even states: a' = sums;  odd states: a' = sums * r  (r = p_lab/p_blank)
//
//  1) k_probs: per (b,t) row softmax over K=512 (one wave per row), emits
//     100 target ratios into glp rows (104 floats) + lb into lbArr.
//  2) k_ctc: ONE WAVE per batch (64 blocks x 64 threads) running the
//     round-9-verified meet-in-the-middle recursion with forward (rows
//     0..511) and backward (rows 1023..512, lane-reversed) INTERLEAVED in
//     the same wave: two independent dependency chains fill each other's
//     VALU latency gaps (round-11 lesson: single-chain DPP recursion is
//     dep-latency-bound at ~176 cy/iter with zero TLP).  Per-lane
//     power-of-2 rescale every 4 steps with INTEGER exponents and
//     bit-constructed split factors (no exp2f on the chain; identical
//     values).  3-buffer register prefetch, 2-chunk slack,
//     sched_barrier(0) after issue clauses.  Epilogue: lane-reversal
//     shuffles, per-state log2 combine -> wave logsumexp, lb sum,
//     atomicAdd of loss/64 into out (k_mean folded in; out zeroed by a
//     capture-safe hipMemsetAsync in kernel_launch).

#define TT 1024
#define BB 64
#define KK 512
#define LL 100
#define ROW 104
#define CH 16

static constexpr float L2E = 1.44269504088896340736f;
static constexpr float LN2 = 0.69314718055994530942f;

// lane i <- lane i-1, lane 0 <- 0  (DPP wave_shr:1, VALU pipe)
__device__ __forceinline__ float dpp_shr1_z(float x) {
  return __builtin_bit_cast(float,
      __builtin_amdgcn_update_dpp(0, __builtin_bit_cast(int, x),
                                  0x138, 0xf, 0xf, true));
}
__device__ __forceinline__ int dpp_shr1_zi(int x) {
  return __builtin_amdgcn_update_dpp(0, x, 0x138, 0xf, 0xf, true);
}

__device__ __forceinline__ float slog2(float x) {
  return x > 0.0f ? log2f(x) : -1.0e30f;
}

__global__ __launch_bounds__(256) void k_probs(const float* __restrict__ logits,
                                               const int* __restrict__ targets,
                                               float* __restrict__ glp,
                                               float* __restrict__ lbArr) {
  const int wid = threadIdx.x >> 6;
  const int lane = threadIdx.x & 63;
  const int row = (blockIdx.x << 2) + wid;      // row = b*T + t
  const int b = row >> 10;                      // T = 1024
  const float* x = logits + (size_t)row * KK;

  __shared__ float sx[4][KK];

  const float4 v0 = reinterpret_cast<const float4*>(x)[lane];
  const float4 v1 = reinterpret_cast<const float4*>(x)[lane + 64];
  float4* sp = reinterpret_cast<float4*>(sx[wid]);
  sp[lane] = v0;
  sp[lane + 64] = v1;

  float m = fmaxf(fmaxf(fmaxf(v0.x, v0.y), fmaxf(v0.z, v0.w)),
                  fmaxf(fmaxf(v1.x, v1.y), fmaxf(v1.z, v1.w)));
  #pragma unroll
  for (int d = 1; d < 64; d <<= 1) m = fmaxf(m, __shfl_xor(m, d));

  float e = exp2f((v0.x - m) * L2E) + exp2f((v0.y - m) * L2E) +
            exp2f((v0.z - m) * L2E) + exp2f((v0.w - m) * L2E) +
            exp2f((v1.x - m) * L2E) + exp2f((v1.y - m) * L2E) +
            exp2f((v1.z - m) * L2E) + exp2f((v1.w - m) * L2E);
  #pragma unroll
  for (int d = 1; d < 64; d <<= 1) e += __shfl_xor(e, d);

  __syncthreads();
  const float xb = sx[wid][0];                  // blank logit

  if (lane < 52) {
    float2 o = {0.0f, 0.0f};
    if (lane >= 1 && lane <= 50) {
      const int* tg = targets + b * LL + (2 * lane - 2);
      const int2 c = *reinterpret_cast<const int2*>(tg);
      o.x = exp2f((sx[wid][c.x] - xb) * L2E);   // ratio p_lab / p_blank
      o.y = exp2f((sx[wid][c.y] - xb) * L2E);
    }
    reinterpret_cast<float2*>(glp + (size_t)row * ROW)[lane] = o;
  }
  // lb = log2(512 * p_blank) = (xb - m)*log2e + 9 - log2(sum exp)
  if (lane == 0) lbArr[row] = (xb - m) * L2E + 9.0f - log2f(e);
}

__global__ __launch_bounds__(64) void k_ctc(const float* __restrict__ glp,
                                            const float* __restrict__ lbArr,
                                            const int* __restrict__ targets,
                                            float* __restrict__ out) {
  const int b = blockIdx.x;
  const int i = threadIdx.x;                    // lane
  const int* tg = targets + b * LL;

  // ---- forward setup: lane i = states 4i..4i+3, rows 0..511 ----
  int offF = 2 + 2 * i;
  if (offF > 102) offF = 102;                   // pad lanes -> zeros
  const float* gbaseF = glp + (size_t)b * TT * ROW + offF;
  float mA = 0.0f, mB = 0.0f;
  if (i > 0 && 2 * i <= LL - 1) mA = (tg[2 * i] != tg[2 * i - 1]) ? 1.0f : 0.0f;
  if (2 * i + 1 <= LL - 1)      mB = (tg[2 * i + 1] != tg[2 * i]) ? 1.0f : 0.0f;
  float F0 = (i == 0) ? 1.0f : 0.0f;            // virtual delta init
  float F1 = 0.0f, F2 = 0.0f, F3 = 0.0f;
  int eaF = 0; float fF1 = 1.0f, fF2 = 1.0f;

  // ---- backward setup: lane j = states of ii = 50-j, rows 1023..512 ----
  const int ii = 50 - i;
  int offB = 2 + 2 * ii;
  if (offB < 0) offB = 0;                       // pad lanes -> zeros
  const float* gbaseB = glp + (size_t)b * TT * ROW + offB;
  float mBb = 0.0f, mAn = 0.0f;
  if (ii >= 0 && 2 * ii + 1 <= LL - 1)
    mBb = (tg[2 * ii + 1] != tg[2 * ii]) ? 1.0f : 0.0f;
  if (ii >= 0 && ii <= 48)
    mAn = (tg[2 * ii + 2] != tg[2 * ii + 1]) ? 1.0f : 0.0f;
  float G0 = (i == 0) ? 1.0f : 0.0f;            // state 200 (ii = 50)
  float G1 = 0.0f, G2 = 0.0f;
  float G3 = (i == 1) ? 1.0f : 0.0f;            // state 199 (ii = 49)
  int eaB = 0; float fB1 = 1.0f, fB2 = 1.0f;

  // per-lane rescale: integer exponents, bit-constructed split factors
  // (identical values to exp2f of integers; no transcendental on chain)
#define RESC(S0, S1, S2, S3, EA, P1, P2)                                   \
  do {                                                                     \
    const float m_ = fmaxf(fmaxf(S0, S1), fmaxf(S2, S3));                  \
    int E_ = (int)((__float_as_uint(m_) >> 23) & 255) - 127;               \
    E_ = (m_ > 0.0f) ? E_ : 0;                                             \
    const float sc_ = __uint_as_float((unsigned)(127 - E_) << 23);         \
    S0 *= sc_; S1 *= sc_; S2 *= sc_; S3 *= sc_;                            \
    EA += E_;                                                              \
    int dE_ = dpp_shr1_zi(EA) - EA;                                        \
    dE_ = dE_ < -250 ? -250 : (dE_ > 250 ? 250 : dE_);                     \
    const int h_ = dE_ / 2;                                                \
    P1 = __uint_as_float((unsigned)(127 + h_) << 23);                      \
    P2 = __uint_as_float((unsigned)(127 + (dE_ - h_)) << 23);              \
  } while (0)

  float2 FA[16], FB[16], FC[16];                // fwd chunk buffers
  float2 GA[16], GB[16], GC[16];                // bwd chunk buffers

#define ISSUE(FBUF, GBUF, CHN)                                             \
  do {                                                                     \
    _Pragma("unroll") for (int j = 0; j < 16; ++j) {                       \
      FBUF[j] = *reinterpret_cast<const float2*>(                          \
          gbaseF + (size_t)((CHN) * CH + j) * ROW);                        \
      GBUF[j] = *reinterpret_cast<const float2*>(                          \
          gbaseB + (size_t)(1023 - ((CHN) * CH + j)) * ROW);               \
    }                                                                      \
    __builtin_amdgcn_sched_barrier(0);                                     \
  } while (0)

  // 16 interleaved fwd+bwd steps: two independent dep chains per iter.
#define COMPUTE(FBUF, GBUF)                                                \
  do {                                                                     \
    _Pragma("unroll") for (int j = 0; j < 16; ++j) {                       \
      const float rx = FBUF[j].x, ry = FBUF[j].y;                          \
      const float s0 = GBUF[j].x, s1 = GBUF[j].y;                          \
      const float A3 = dpp_shr1_z(F3) * fF1 * fF2;                         \
      const float s2 = dpp_shr1_z(s0);          /* ratio of label 2ii+2 */ \
      const float H0 = dpp_shr1_z(G0) * fB1 * fB2;                         \
      const float H1 = dpp_shr1_z(G1) * fB1 * fB2;                         \
      const float nF0 = F0 + A3;                                           \
      const float nF1 = (F0 + F1 + mA * A3) * rx;                          \
      const float nF2 = F1 + F2;                                           \
      const float nF3 = (F2 + F3 + mB * F1) * ry;                          \
      const float u = s0 * G1;                                             \
      const float v = s1 * G3;                                             \
      const float nG0 = G0 + u;                                            \
      const float nG1 = u + fmaf(mBb, v, G2);                              \
      const float nG2 = G2 + v;                                            \
      const float nG3 = v + fmaf(mAn, s2 * H1, H0);                        \
      F0 = nF0; F1 = nF1; F2 = nF2; F3 = nF3;                              \
      G0 = nG0; G1 = nG1; G2 = nG2; G3 = nG3;                              \
      if ((j & 3) == 3) {                                                  \
        RESC(F0, F1, F2, F3, eaF, fF1, fF2);                               \
        RESC(G0, G1, G2, G3, eaB, fB1, fB2);                               \
      }                                                                    \
    }                                                                      \
  } while (0)

  ISSUE(FA, GA, 0);
  ISSUE(FB, GB, 1);
  for (int c = 0; c < 30; c += 3) {
    ISSUE(FC, GC, c + 2); COMPUTE(FA, GA);
    ISSUE(FA, GA, c + 3); COMPUTE(FB, GB);
    ISSUE(FB, GB, c + 4); COMPUTE(FC, GC);
  }
  COMPUTE(FA, GA);                              // chunk 30
  COMPUTE(FB, GB);                              // chunk 31
#undef ISSUE
#undef COMPUTE
#undef RESC

  // ---- combine: fwd lane i pairs with bwd lane 50-i (63 = zero pad) ----
  const int gj = (i <= 50) ? (50 - i) : 63;
  const float g0 = __shfl(G0, gj);
  const float g1 = __shfl(G1, gj);
  const float g2 = __shfl(G2, gj);
  const float g3 = __shfl(G3, gj);
  const float ebf = (float)__shfl(eaB, gj);
  const float eff = (float)eaF;

  float w0 = slog2(F0) + eff + slog2(g0) + ebf;
  float w1 = slog2(F1) + eff + slog2(g1) + ebf;
  float w2 = slog2(F2) + eff + slog2(g2) + ebf;
  float w3 = slog2(F3) + eff + slog2(g3) + ebf;
  float wm = fmaxf(fmaxf(w0, w1), fmaxf(w2, w3));
  #pragma unroll
  for (int d = 1; d < 64; d <<= 1) wm = fmaxf(wm, __shfl_xor(wm, d));
  float ss = exp2f(w0 - wm) + exp2f(w1 - wm) +
             exp2f(w2 - wm) + exp2f(w3 - wm);
  #pragma unroll
  for (int d = 1; d < 64; d <<= 1) ss += __shfl_xor(ss, d);

  // sum lb over all 1024 rows (coalesced float4 reads)
  float s4 = 0.0f;
  const float4* lbv = reinterpret_cast<const float4*>(lbArr + (size_t)b * TT);
  #pragma unroll
  for (int j = 0; j < 4; ++j) {
    const float4 v = lbv[i + 64 * j];
    s4 += (v.x + v.y) + (v.z + v.w);
  }
  #pragma unroll
  for (int d = 1; d < 64; d <<= 1) s4 += __shfl_xor(s4, d);

  if (i == 0) {
    float loss = 0.0f;                          // zero_infinity
    if (wm > -1.0e29f) {
      const float logl2 = wm + log2f(ss) + s4 - (float)(TT * 9);
      loss = -(logl2 * LN2) / (float)LL;
    }
    atomicAdd(out, loss * (1.0f / (float)BB));  // mean folded in
  }
}

extern "C" void kernel_launch(void* const* d_in, const int* in_sizes, int n_in,
                              void* d_out, int out_size, void* d_ws, size_t ws_size,
                              hipStream_t stream) {
  const float* logits = (const float*)d_in[0];   // (64, 1024, 512) f32
  const int* targets = (const int*)d_in[1];      // (64, 100) i32
  float* out = (float*)d_out;                    // scalar f32

  float* glp = (float*)d_ws;                     // 64*1024*104 f32
  float* lbArr = glp + (size_t)BB * TT * ROW;    // 64*1024 f32

  hipMemsetAsync(out, 0, sizeof(float), stream); // capture-safe (R10)
  hipLaunchKernelGGL(k_probs, dim3(BB * TT / 4), dim3(256), 0, stream,
                     logits, targets, glp, lbArr);
  hipLaunchKernelGGL(k_ctc, dim3(BB), dim3(64), 0, stream,
                     glp, lbArr, targets, out);
}

// Round 13
// 60.155 us; speedup vs baseline: 30.6657x; 1.3459x over previous
//
#include <hip/hip_runtime.h>
#include <hip/hip_fp16.h>

// CTC loss (blank=0, mean reduction, zero_infinity) for
// B=64, T=1024, K=512, L=100  ->  S = 2L+1 = 201 extended states.
//
// Ratio formulation: factor prod_t p_blank(t) out of all alpha states.
//   even states: a' = sums;  odd states: a' = sums * r  (r = p_lab/p_blank)
//
// Round-13 insight: k_ctc cost = 512*15ns (VALU chain) + ~31us FIXED, the
// fixed part being the per-block 512KB glp stream through one CU's miss
// resources at LLC latency. So: (1) ratios packed fp16x2 -> 4B/lane/row
// (4 cache lines per row instead of 8; 128KB per direction); (2) fwd and
// bwd run in SEPARATE BLOCKS (2 CUs' worth of memory concurrency per
// batch); (3) tiny k_final combines.
//
//  1) k_probs: per (b,t) row softmax (one wave per row): 100 target
//     ratios -> pk[row][64] fp16x2 words (word w = labels 2w,2w+1;
//     words 50..63 zero) + lb = log2(512*p_blank) -> lbArr (fp32).
//  2) k_ctc: 128 blocks x 64 threads; block 2b+d: d=0 forward rows
//     0..511 (lane i = states 4i..4i+3), d=1 backward rows 1023..512
//     (lane j = states of ii=50-j; both directions use the verified
//     wave_shr:1 DPP). Per-lane power-of-2 rescale every 4 steps with
//     integer exponents + bit-built split factors (R12, verified).
//     3-buffer register prefetch, 2-chunk slack, sched_barrier(0).
//     Publishes 4 states + exponent per lane to ws.
//  3) k_final: 64 blocks x 64 threads: per-state log2 combine -> wave
//     logsumexp, lb sum, atomicAdd(out, loss/64). out zeroed by
//     capture-safe hipMemsetAsync.

#define TT 1024
#define BB 64
#define KK 512
#define LL 100
#define CH 16

static constexpr float L2E = 1.44269504088896340736f;
static constexpr float LN2 = 0.69314718055994530942f;

// lane i <- lane i-1, lane 0 <- 0  (DPP wave_shr:1, VALU pipe)
__device__ __forceinline__ float dpp_shr1_z(float x) {
  return __builtin_bit_cast(float,
      __builtin_amdgcn_update_dpp(0, __builtin_bit_cast(int, x),
                                  0x138, 0xf, 0xf, true));
}
__device__ __forceinline__ int dpp_shr1_zi(int x) {
  return __builtin_amdgcn_update_dpp(0, x, 0x138, 0xf, 0xf, true);
}

__device__ __forceinline__ float slog2(float x) {
  return x > 0.0f ? log2f(x) : -1.0e30f;
}

__device__ __forceinline__ float2 upk(unsigned u) {
  return __half22float2(__builtin_bit_cast(__half2, u));
}

__global__ __launch_bounds__(256) void k_probs(const float* __restrict__ logits,
                                               const int* __restrict__ targets,
                                               unsigned* __restrict__ pk,
                                               float* __restrict__ lbArr) {
  const int wid = threadIdx.x >> 6;
  const int lane = threadIdx.x & 63;
  const int row = (blockIdx.x << 2) + wid;      // row = b*T + t
  const int b = row >> 10;                      // T = 1024
  const float* x = logits + (size_t)row * KK;

  __shared__ float sx[4][KK];

  const float4 v0 = reinterpret_cast<const float4*>(x)[lane];
  const float4 v1 = reinterpret_cast<const float4*>(x)[lane + 64];
  float4* sp = reinterpret_cast<float4*>(sx[wid]);
  sp[lane] = v0;
  sp[lane + 64] = v1;

  float m = fmaxf(fmaxf(fmaxf(v0.x, v0.y), fmaxf(v0.z, v0.w)),
                  fmaxf(fmaxf(v1.x, v1.y), fmaxf(v1.z, v1.w)));
  #pragma unroll
  for (int d = 1; d < 64; d <<= 1) m = fmaxf(m, __shfl_xor(m, d));

  float e = exp2f((v0.x - m) * L2E) + exp2f((v0.y - m) * L2E) +
            exp2f((v0.z - m) * L2E) + exp2f((v0.w - m) * L2E) +
            exp2f((v1.x - m) * L2E) + exp2f((v1.y - m) * L2E) +
            exp2f((v1.z - m) * L2E) + exp2f((v1.w - m) * L2E);
  #pragma unroll
  for (int d = 1; d < 64; d <<= 1) e += __shfl_xor(e, d);

  __syncthreads();
  const float xb = sx[wid][0];                  // blank logit

  float ox = 0.0f, oy = 0.0f;
  if (lane >= 1 && lane <= 50) {
    const int2 c = *reinterpret_cast<const int2*>(
        targets + b * LL + (2 * lane - 2));
    ox = exp2f((sx[wid][c.x] - xb) * L2E);      // ratio p_lab / p_blank
    oy = exp2f((sx[wid][c.y] - xb) * L2E);
  }
  // word w holds labels 2w, 2w+1; words 50..63 are zero pads.
  const int word = (lane == 0) ? 63 : (lane - 1);
  const __half2 h = __floats2half2_rn(ox, oy);
  pk[(size_t)row * 64 + word] = __builtin_bit_cast(unsigned, h);

  // lb = log2(512 * p_blank) = (xb - m)*log2e + 9 - log2(sum exp)
  if (lane == 0) lbArr[row] = (xb - m) * L2E + 9.0f - log2f(e);
}

__global__ __launch_bounds__(64) void k_ctc(const unsigned* __restrict__ pk,
                                            const int* __restrict__ targets,
                                            float* __restrict__ ws) {
  const int blk = blockIdx.x;
  const int b = blk >> 1;
  const int dir = blk & 1;                      // 0 = forward, 1 = backward
  const int i = threadIdx.x;                    // lane
  const int* tg = targets + b * LL;

  float S0 = 0.0f, S1 = 0.0f, S2 = 0.0f, S3 = 0.0f;
  int ea = 0;
  float f1 = 1.0f, f2 = 1.0f;

  // per-lane rescale: integer exponents, bit-constructed split factors
#define RESC()                                                             \
  do {                                                                     \
    const float m_ = fmaxf(fmaxf(S0, S1), fmaxf(S2, S3));                  \
    int E_ = (int)((__float_as_uint(m_) >> 23) & 255) - 127;               \
    E_ = (m_ > 0.0f) ? E_ : 0;                                             \
    const float sc_ = __uint_as_float((unsigned)(127 - E_) << 23);         \
    S0 *= sc_; S1 *= sc_; S2 *= sc_; S3 *= sc_;                            \
    ea += E_;                                                              \
    int dE_ = dpp_shr1_zi(ea) - ea;                                        \
    dE_ = dE_ < -250 ? -250 : (dE_ > 250 ? 250 : dE_);                     \
    const int h_ = dE_ / 2;                                                \
    f1 = __uint_as_float((unsigned)(127 + h_) << 23);                      \
    f2 = __uint_as_float((unsigned)(127 + (dE_ - h_)) << 23);              \
  } while (0)

  unsigned RA[16], RB[16], RC[16];              // fp16x2 chunk buffers

  if (dir == 0) {
    // ---------- forward: rows 0..511, lane i = states 4i..4i+3 ----------
    const unsigned* gb = pk + (size_t)b * TT * 64 + i;  // word i
    float mA = 0.0f, mB = 0.0f;
    if (i > 0 && 2 * i <= LL - 1)
      mA = (tg[2 * i] != tg[2 * i - 1]) ? 1.0f : 0.0f;
    if (2 * i + 1 <= LL - 1)
      mB = (tg[2 * i + 1] != tg[2 * i]) ? 1.0f : 0.0f;
    S0 = (i == 0) ? 1.0f : 0.0f;                // virtual delta init

#define FISSUE(BUF, CHN)                                                   \
    do {                                                                   \
      _Pragma("unroll") for (int j = 0; j < 16; ++j)                       \
        BUF[j] = gb[(size_t)((CHN) * CH + j) * 64];                        \
      __builtin_amdgcn_sched_barrier(0);                                   \
    } while (0)
#define FCOMPUTE(BUF)                                                      \
    do {                                                                   \
      _Pragma("unroll") for (int j = 0; j < 16; ++j) {                     \
        const float2 r = upk(BUF[j]);                                      \
        const float A3 = dpp_shr1_z(S3) * f1 * f2;                         \
        const float n0 = S0 + A3;                                          \
        const float n1 = (S0 + S1 + mA * A3) * r.x;                        \
        const float n2 = S1 + S2;                                          \
        const float n3 = (S2 + S3 + mB * S1) * r.y;                        \
        S0 = n0; S1 = n1; S2 = n2; S3 = n3;                                \
        if ((j & 3) == 3) RESC();                                          \
      }                                                                    \
    } while (0)

    FISSUE(RA, 0);
    FISSUE(RB, 1);
    for (int c = 0; c < 30; c += 3) {
      FISSUE(RC, c + 2); FCOMPUTE(RA);
      FISSUE(RA, c + 3); FCOMPUTE(RB);
      FISSUE(RB, c + 4); FCOMPUTE(RC);
    }
    FCOMPUTE(RA);                               // chunk 30
    FCOMPUTE(RB);                               // chunk 31
#undef FISSUE
#undef FCOMPUTE
  } else {
    // ------- backward: rows 1023..512, lane j = states of ii = 50-j -----
    const int ii = 50 - i;
    const int w = (ii >= 0) ? ii : 50;          // word 50 = zeros (pad)
    const unsigned* gb = pk + (size_t)b * TT * 64 + w;
    float mBb = 0.0f, mAn = 0.0f;
    if (ii >= 0 && 2 * ii + 1 <= LL - 1)
      mBb = (tg[2 * ii + 1] != tg[2 * ii]) ? 1.0f : 0.0f;
    if (ii >= 0 && ii <= 48)
      mAn = (tg[2 * ii + 2] != tg[2 * ii + 1]) ? 1.0f : 0.0f;
    if (i == 0) S0 = 1.0f;                      // state 200 (ii = 50)
    if (i == 1) S3 = 1.0f;                      // state 199 (ii = 49)

#define BISSUE(BUF, CHN)                                                   \
    do {                                                                   \
      _Pragma("unroll") for (int j = 0; j < 16; ++j)                       \
        BUF[j] = gb[(size_t)(1023 - ((CHN) * CH + j)) * 64];               \
      __builtin_amdgcn_sched_barrier(0);                                   \
    } while (0)
#define BCOMPUTE(BUF)                                                      \
    do {                                                                   \
      _Pragma("unroll") for (int j = 0; j < 16; ++j) {                     \
        const float2 r = upk(BUF[j]);                                      \
        const float s2 = dpp_shr1_z(r.x);       /* label 2ii+2 ratio */    \
        const float H0 = dpp_shr1_z(S0) * f1 * f2;                         \
        const float H1 = dpp_shr1_z(S1) * f1 * f2;                         \
        const float u = r.x * S1;                                          \
        const float v = r.y * S3;                                          \
        const float n0 = S0 + u;                                           \
        const float n1 = u + fmaf(mBb, v, S2);                             \
        const float n2 = S2 + v;                                           \
        const float n3 = v + fmaf(mAn, s2 * H1, H0);                       \
        S0 = n0; S1 = n1; S2 = n2; S3 = n3;                                \
        if ((j & 3) == 3) RESC();                                          \
      }                                                                    \
    } while (0)

    BISSUE(RA, 0);
    BISSUE(RB, 1);
    for (int c = 0; c < 30; c += 3) {
      BISSUE(RC, c + 2); BCOMPUTE(RA);
      BISSUE(RA, c + 3); BCOMPUTE(RB);
      BISSUE(RB, c + 4); BCOMPUTE(RC);
    }
    BCOMPUTE(RA);                               // chunk 30 (rows 543..528)
    BCOMPUTE(RB);                               // chunk 31 (rows 527..512)
#undef BISSUE
#undef BCOMPUTE
  }
#undef RESC

  // publish 4 states + exponent for this lane
  float* W = ws + (size_t)blk * 5 * 64;
  W[0 * 64 + i] = S0;
  W[1 * 64 + i] = S1;
  W[2 * 64 + i] = S2;
  W[3 * 64 + i] = S3;
  W[4 * 64 + i] = (float)ea;
}

__global__ __launch_bounds__(64) void k_final(const float* __restrict__ ws,
                                              const float* __restrict__ lbArr,
                                              float* __restrict__ out) {
  const int b = blockIdx.x;
  const int i = threadIdx.x;

  const float* WF = ws + (size_t)(2 * b) * 5 * 64;
  const float* WG = ws + (size_t)(2 * b + 1) * 5 * 64;
  const int gj = (i <= 50) ? (50 - i) : 63;     // bwd lane w/ states 4i..

  const float F0 = WF[0 * 64 + i], F1 = WF[1 * 64 + i];
  const float F2 = WF[2 * 64 + i], F3 = WF[3 * 64 + i];
  const float eff = WF[4 * 64 + i];
  const float G0 = WG[0 * 64 + gj], G1 = WG[1 * 64 + gj];
  const float G2 = WG[2 * 64 + gj], G3 = WG[3 * 64 + gj];
  const float ebf = WG[4 * 64 + gj];

  float w0 = slog2(F0) + eff + slog2(G0) + ebf;
  float w1 = slog2(F1) + eff + slog2(G1) + ebf;
  float w2 = slog2(F2) + eff + slog2(G2) + ebf;
  float w3 = slog2(F3) + eff + slog2(G3) + ebf;
  float wm = fmaxf(fmaxf(w0, w1), fmaxf(w2, w3));
  #pragma unroll
  for (int d = 1; d < 64; d <<= 1) wm = fmaxf(wm, __shfl_xor(wm, d));
  float ss = exp2f(w0 - wm) + exp2f(w1 - wm) +
             exp2f(w2 - wm) + exp2f(w3 - wm);
  #pragma unroll
  for (int d = 1; d < 64; d <<= 1) ss += __shfl_xor(ss, d);

  // sum lb over all 1024 rows (coalesced float4 reads)
  float s4 = 0.0f;
  const float4* lbv = reinterpret_cast<const float4*>(lbArr + (size_t)b * TT);
  #pragma unroll
  for (int j = 0; j < 4; ++j) {
    const float4 v = lbv[i + 64 * j];
    s4 += (v.x + v.y) + (v.z + v.w);
  }
  #pragma unroll
  for (int d = 1; d < 64; d <<= 1) s4 += __shfl_xor(s4, d);

  if (i == 0) {
    float loss = 0.0f;                          // zero_infinity
    if (wm > -1.0e29f) {
      const float logl2 = wm + log2f(ss) + s4 - (float)(TT * 9);
      loss = -(logl2 * LN2) / (float)LL;
    }
    atomicAdd(out, loss * (1.0f / (float)BB));  // mean folded in
  }
}

extern "C" void kernel_launch(void* const* d_in, const int* in_sizes, int n_in,
                              void* d_out, int out_size, void* d_ws, size_t ws_size,
                              hipStream_t stream) {
  const float* logits = (const float*)d_in[0];   // (64, 1024, 512) f32
  const int* targets = (const int*)d_in[1];      // (64, 100) i32
  float* out = (float*)d_out;                    // scalar f32

  unsigned* pk = (unsigned*)d_ws;                // 64*1024*64 u32 (4 MB)
  float* lbArr = (float*)d_ws + (size_t)BB * TT * 64;  // 64*1024 f32
  float* ws = lbArr + (size_t)BB * TT;           // 128*5*64 f32

  hipMemsetAsync(out, 0, sizeof(float), stream); // capture-safe
  hipLaunchKernelGGL(k_probs, dim3(BB * TT / 4), dim3(256), 0, stream,
                     logits, targets, pk, lbArr);
  hipLaunchKernelGGL(k_ctc, dim3(2 * BB), dim3(64), 0, stream,
                     pk, targets, ws);
  hipLaunchKernelGGL(k_final, dim3(BB), dim3(64), 0, stream,
                     ws, lbArr, out);
}

// Round 14
// 52.369 us; speedup vs baseline: 35.2248x; 1.1487x over previous
//
#include <hip/hip_runtime.h>
#include <hip/hip_fp16.h>

// CTC loss (blank=0, mean reduction, zero_infinity) for
// B=64, T=1024, K=512, L=100  ->  S = 2L+1 = 201 extended states.
//
// Ratio formulation: factor prod_t p_blank(t) out of all alpha states.
//   even states: a' = sums;  odd states: a' = sums * r  (r = p_lab/p_blank)
//
// Round-14: consolidation. 2 dispatches total.
//  1) k_probs: per (b,t) row softmax (one wave per row): 100 target
//     ratios -> fp16x2, PAIR-PACKED pk[b][t/2][word][2] (word w = labels
//     2w,2w+1; words 50..63 zero; element = t&1) + lb = log2(512*p_blank)
//     -> lbArr. Block 0 thread 0 zeroes out[] (runs before k_ctc).
//  2) k_ctc: 64 blocks x 128 threads (R9-verified structure): wave 0 =
//     forward rows 0..511 (lane i = states 4i..4i+3), wave 1 = backward
//     rows 1023..512 (lane j = states of ii=50-j; both directions use the
//     verified wave_shr:1 DPP).  Pair loads: one uint2 per lane per row-
//     pair (8 loads/16-row chunk).  4 register buffers, 3-chunk slack,
//     sched_barrier(0) after issue clauses.  Per-lane power-of-2 rescale
//     every 8 steps (R2-R7-verified window) with integer exponents +
//     bit-built split factors; cross-lane terms scaled by (x*f1)*f2.
//     Epilogue (R9/R10-verified): bwd publishes states+exponent+lb via
//     LDS, fwd combines per-state in log2 domain -> wave logsumexp,
//     atomicAdd(out, loss/64).

#define TT 1024
#define BB 64
#define KK 512
#define LL 100

static constexpr float L2E = 1.44269504088896340736f;
static constexpr float LN2 = 0.69314718055994530942f;

// lane i <- lane i-1, lane 0 <- 0  (DPP wave_shr:1, VALU pipe)
__device__ __forceinline__ float dpp_shr1_z(float x) {
  return __builtin_bit_cast(float,
      __builtin_amdgcn_update_dpp(0, __builtin_bit_cast(int, x),
                                  0x138, 0xf, 0xf, true));
}
__device__ __forceinline__ int dpp_shr1_zi(int x) {
  return __builtin_amdgcn_update_dpp(0, x, 0x138, 0xf, 0xf, true);
}

__device__ __forceinline__ float slog2(float x) {
  return x > 0.0f ? log2f(x) : -1.0e30f;
}

__device__ __forceinline__ float2 upk(unsigned u) {
  return __half22float2(__builtin_bit_cast(__half2, u));
}

__global__ __launch_bounds__(256) void k_probs(const float* __restrict__ logits,
                                               const int* __restrict__ targets,
                                               unsigned* __restrict__ pk,
                                               float* __restrict__ lbArr,
                                               float* __restrict__ out) {
  const int wid = threadIdx.x >> 6;
  const int lane = threadIdx.x & 63;
  const int row = (blockIdx.x << 2) + wid;      // row = b*T + t
  const int b = row >> 10;                      // T = 1024
  const float* x = logits + (size_t)row * KK;

  if (blockIdx.x == 0 && threadIdx.x == 0) out[0] = 0.0f;  // pre-k_ctc

  __shared__ float sx[4][KK];

  const float4 v0 = reinterpret_cast<const float4*>(x)[lane];
  const float4 v1 = reinterpret_cast<const float4*>(x)[lane + 64];
  float4* sp = reinterpret_cast<float4*>(sx[wid]);
  sp[lane] = v0;
  sp[lane + 64] = v1;

  float m = fmaxf(fmaxf(fmaxf(v0.x, v0.y), fmaxf(v0.z, v0.w)),
                  fmaxf(fmaxf(v1.x, v1.y), fmaxf(v1.z, v1.w)));
  #pragma unroll
  for (int d = 1; d < 64; d <<= 1) m = fmaxf(m, __shfl_xor(m, d));

  float e = exp2f((v0.x - m) * L2E) + exp2f((v0.y - m) * L2E) +
            exp2f((v0.z - m) * L2E) + exp2f((v0.w - m) * L2E) +
            exp2f((v1.x - m) * L2E) + exp2f((v1.y - m) * L2E) +
            exp2f((v1.z - m) * L2E) + exp2f((v1.w - m) * L2E);
  #pragma unroll
  for (int d = 1; d < 64; d <<= 1) e += __shfl_xor(e, d);

  __syncthreads();
  const float xb = sx[wid][0];                  // blank logit

  float ox = 0.0f, oy = 0.0f;
  if (lane >= 1 && lane <= 50) {
    const int2 c = *reinterpret_cast<const int2*>(
        targets + b * LL + (2 * lane - 2));
    ox = exp2f((sx[wid][c.x] - xb) * L2E);      // ratio p_lab / p_blank
    oy = exp2f((sx[wid][c.y] - xb) * L2E);
  }
  // word w holds labels 2w,2w+1; words 50..63 zero pads. pair element = t&1
  const int word = (lane == 0) ? 63 : (lane - 1);
  const __half2 h = __floats2half2_rn(ox, oy);
  pk[(size_t)(row >> 1) * 128 + word * 2 + (row & 1)] =
      __builtin_bit_cast(unsigned, h);

  // lb = log2(512 * p_blank) = (xb - m)*log2e + 9 - log2(sum exp)
  if (lane == 0) lbArr[row] = (xb - m) * L2E + 9.0f - log2f(e);
}

__global__ __launch_bounds__(128) void k_ctc(const unsigned* __restrict__ pk,
                                             const float* __restrict__ lbArr,
                                             const int* __restrict__ targets,
                                             float* __restrict__ out) {
  const int b = blockIdx.x;
  const int lane = threadIdx.x & 63;
  const int wv = threadIdx.x >> 6;              // 0 = forward, 1 = backward
  const int i = lane;
  const int* tg = targets + b * LL;

  __shared__ float sG[6][64];

  float S0 = 0.0f, S1 = 0.0f, S2 = 0.0f, S3 = 0.0f;
  int ea = 0;
  float f1 = 1.0f, f2 = 1.0f;
  float s4 = 0.0f;

  // per-lane rescale: integer exponents, bit-constructed split factors
#define RESC()                                                             \
  do {                                                                     \
    const float m_ = fmaxf(fmaxf(S0, S1), fmaxf(S2, S3));                  \
    int E_ = (int)((__float_as_uint(m_) >> 23) & 255) - 127;               \
    E_ = (m_ > 0.0f) ? E_ : 0;                                             \
    const float sc_ = __uint_as_float((unsigned)(127 - E_) << 23);         \
    S0 *= sc_; S1 *= sc_; S2 *= sc_; S3 *= sc_;                            \
    ea += E_;                                                              \
    int dE_ = dpp_shr1_zi(ea) - ea;                                        \
    dE_ = dE_ < -250 ? -250 : (dE_ > 250 ? 250 : dE_);                     \
    const int h_ = dE_ / 2;                                                \
    f1 = __uint_as_float((unsigned)(127 + h_) << 23);                      \
    f2 = __uint_as_float((unsigned)(127 + (dE_ - h_)) << 23);              \
  } while (0)

  uint2 RA[8], RB[8], RC[8], RD[8];             // pair buffers (8/chunk)

  if (wv == 0) {
    // ---------- forward: rows 0..511, lane i = states 4i..4i+3 ----------
    const unsigned* gb = pk + (size_t)b * 512 * 128 + i * 2;  // word i
    float mA = 0.0f, mB = 0.0f;
    if (i > 0 && 2 * i <= LL - 1)
      mA = (tg[2 * i] != tg[2 * i - 1]) ? 1.0f : 0.0f;
    if (2 * i + 1 <= LL - 1)
      mB = (tg[2 * i + 1] != tg[2 * i]) ? 1.0f : 0.0f;
    S0 = (i == 0) ? 1.0f : 0.0f;                // virtual delta init

    // pair tp = CHN*8+j -> rows 2tp (.x) then 2tp+1 (.y)
#define FISSUE(BUF, CHN)                                                   \
    do {                                                                   \
      if ((CHN) < 32) {                                                    \
        _Pragma("unroll") for (int j = 0; j < 8; ++j)                      \
          BUF[j] = *reinterpret_cast<const uint2*>(                        \
              gb + (size_t)((CHN) * 8 + j) * 128);                         \
        __builtin_amdgcn_sched_barrier(0);                                 \
      }                                                                    \
    } while (0)
#define FSTEP(R)                                                           \
    do {                                                                   \
      const float A3 = dpp_shr1_z(S3) * f1 * f2;                           \
      const float n0 = S0 + A3;                                            \
      const float n1 = (S0 + S1 + mA * A3) * (R).x;                        \
      const float n2 = S1 + S2;                                            \
      const float n3 = (S2 + S3 + mB * S1) * (R).y;                        \
      S0 = n0; S1 = n1; S2 = n2; S3 = n3;                                  \
    } while (0)
#define FCOMPUTE(BUF)                                                      \
    do {                                                                   \
      _Pragma("unroll") for (int j = 0; j < 8; ++j) {                      \
        const float2 re = upk(BUF[j].x);                                   \
        FSTEP(re);                                                         \
        const float2 ro = upk(BUF[j].y);                                   \
        FSTEP(ro);                                                         \
        if ((j & 3) == 3) RESC();               /* every 8 steps */        \
      }                                                                    \
    } while (0)

    FISSUE(RA, 0); FISSUE(RB, 1); FISSUE(RC, 2);
    for (int c = 0; c < 32; c += 4) {
      FISSUE(RD, c + 3); FCOMPUTE(RA);
      FISSUE(RA, c + 4); FCOMPUTE(RB);
      FISSUE(RB, c + 5); FCOMPUTE(RC);
      FISSUE(RC, c + 6); FCOMPUTE(RD);
    }
#undef FISSUE
#undef FSTEP
#undef FCOMPUTE

    // lb partial: rows 0..511
    const float4* lbv =
        reinterpret_cast<const float4*>(lbArr + (size_t)b * TT);
    #pragma unroll
    for (int j = 0; j < 2; ++j) {
      const float4 v = lbv[i + 64 * j];
      s4 += (v.x + v.y) + (v.z + v.w);
    }
    #pragma unroll
    for (int d = 1; d < 64; d <<= 1) s4 += __shfl_xor(s4, d);
  } else {
    // ------- backward: rows 1023..512, lane j = states of ii = 50-j -----
    const int ii = 50 - i;
    const int w = (ii >= 0) ? ii : 50;          // word 50 = zeros (pad)
    const unsigned* gb = pk + (size_t)b * 512 * 128 + w * 2;
    float mBb = 0.0f, mAn = 0.0f;
    if (ii >= 0 && 2 * ii + 1 <= LL - 1)
      mBb = (tg[2 * ii + 1] != tg[2 * ii]) ? 1.0f : 0.0f;
    if (ii >= 0 && ii <= 48)
      mAn = (tg[2 * ii + 2] != tg[2 * ii + 1]) ? 1.0f : 0.0f;
    if (i == 0) S0 = 1.0f;                      // state 200 (ii = 50)
    if (i == 1) S3 = 1.0f;                      // state 199 (ii = 49)

    // pair tp = 511-(CHN*8+j) -> rows 2tp+1 (.y) then 2tp (.x), descending
#define BISSUE(BUF, CHN)                                                   \
    do {                                                                   \
      if ((CHN) < 32) {                                                    \
        _Pragma("unroll") for (int j = 0; j < 8; ++j)                      \
          BUF[j] = *reinterpret_cast<const uint2*>(                        \
              gb + (size_t)(511 - ((CHN) * 8 + j)) * 128);                 \
        __builtin_amdgcn_sched_barrier(0);                                 \
      }                                                                    \
    } while (0)
#define BSTEP(R)                                                           \
    do {                                                                   \
      const float s2 = dpp_shr1_z((R).x);       /* label 2ii+2 ratio */    \
      const float H0 = dpp_shr1_z(S0) * f1 * f2;                           \
      const float H1 = dpp_shr1_z(S1) * f1 * f2;                           \
      const float u = (R).x * S1;                                          \
      const float v = (R).y * S3;                                          \
      const float n0 = S0 + u;                                             \
      const float n1 = u + fmaf(mBb, v, S2);                               \
      const float n2 = S2 + v;                                             \
      const float n3 = v + fmaf(mAn, s2 * H1, H0);                         \
      S0 = n0; S1 = n1; S2 = n2; S3 = n3;                                  \
    } while (0)
#define BCOMPUTE(BUF)                                                      \
    do {                                                                   \
      _Pragma("unroll") for (int j = 0; j < 8; ++j) {                      \
        const float2 ro = upk(BUF[j].y);                                   \
        BSTEP(ro);                                                         \
        const float2 re = upk(BUF[j].x);                                   \
        BSTEP(re);                                                         \
        if ((j & 3) == 3) RESC();               /* every 8 steps */        \
      }                                                                    \
    } while (0)

    BISSUE(RA, 0); BISSUE(RB, 1); BISSUE(RC, 2);
    for (int c = 0; c < 32; c += 4) {
      BISSUE(RD, c + 3); BCOMPUTE(RA);
      BISSUE(RA, c + 4); BCOMPUTE(RB);
      BISSUE(RB, c + 5); BCOMPUTE(RC);
      BISSUE(RC, c + 6); BCOMPUTE(RD);
    }
#undef BISSUE
#undef BSTEP
#undef BCOMPUTE

    sG[0][lane] = S0; sG[1][lane] = S1; sG[2][lane] = S2; sG[3][lane] = S3;
    sG[4][lane] = (float)ea;

    // lb partial: rows 512..1023
    const float4* lbv =
        reinterpret_cast<const float4*>(lbArr + (size_t)b * TT);
    #pragma unroll
    for (int j = 0; j < 2; ++j) {
      const float4 v = lbv[128 + lane + 64 * j];
      s4 += (v.x + v.y) + (v.z + v.w);
    }
    #pragma unroll
    for (int d = 1; d < 64; d <<= 1) s4 += __shfl_xor(s4, d);
    if (lane == 0) sG[5][0] = s4;
  }
#undef RESC

  __syncthreads();                              // backward publishes sG

  if (wv == 0) {
    const int gj = (i <= 50) ? (50 - i) : 63;   // bwd lane w/ states 4i..
    const float eb = sG[4][gj];
    const float eff = (float)ea;
    float w0 = slog2(S0) + eff + slog2(sG[0][gj]) + eb;
    float w1 = slog2(S1) + eff + slog2(sG[1][gj]) + eb;
    float w2 = slog2(S2) + eff + slog2(sG[2][gj]) + eb;
    float w3 = slog2(S3) + eff + slog2(sG[3][gj]) + eb;
    float wm = fmaxf(fmaxf(w0, w1), fmaxf(w2, w3));
    #pragma unroll
    for (int d = 1; d < 64; d <<= 1) wm = fmaxf(wm, __shfl_xor(wm, d));
    float ss = exp2f(w0 - wm) + exp2f(w1 - wm) +
               exp2f(w2 - wm) + exp2f(w3 - wm);
    #pragma unroll
    for (int d = 1; d < 64; d <<= 1) ss += __shfl_xor(ss, d);

    if (i == 0) {
      const float lbsum = s4 + sG[5][0];        // fwd + bwd halves
      float loss = 0.0f;                        // zero_infinity
      if (wm > -1.0e29f) {
        const float logl2 = wm + log2f(ss) + lbsum - (float)(TT * 9);
        loss = -(logl2 * LN2) / (float)LL;
      }
      atomicAdd(out, loss * (1.0f / (float)BB));
    }
  }
}

extern "C" void kernel_launch(void* const* d_in, const int* in_sizes, int n_in,
                              void* d_out, int out_size, void* d_ws, size_t ws_size,
                              hipStream_t stream) {
  const float* logits = (const float*)d_in[0];   // (64, 1024, 512) f32
  const int* targets = (const int*)d_in[1];      // (64, 100) i32
  float* out = (float*)d_out;                    // scalar f32

  unsigned* pk = (unsigned*)d_ws;                // 64*512*128 u32 (16 MB)
  float* lbArr = (float*)d_ws + (size_t)BB * 512 * 128;  // 64*1024 f32

  hipLaunchKernelGGL(k_probs, dim3(BB * TT / 4), dim3(256), 0, stream,
                     logits, targets, pk, lbArr, out);
  hipLaunchKernelGGL(k_ctc, dim3(BB), dim3(128), 0, stream,
                     pk, lbArr, targets, out);
}

// Round 15
// 51.630 us; speedup vs baseline: 35.7291x; 1.0143x over previous
//
#include <hip/hip_runtime.h>
#include <hip/hip_fp16.h>

// CTC loss (blank=0, mean reduction, zero_infinity) for
// B=64, T=1024, K=512, L=100  ->  S = 2L+1 = 201 extended states.
//
// Ratio formulation: factor prod_t p_blank(t) out of all alpha states.
//   even states: a' = sums;  odd states: a' = sums * r  (r = p_lab/p_blank)
//
// Round-15: deepen k_ctc's register prefetch (4 -> 8 buffers, 7-chunk
// slack ~2800 cy: covers cold-HBM latency with margin; round-14 left
// ~15us of exposed load latency at 3-chunk slack) + early-issue the lb
// partial-sum loads. Math identical to the verified R14 kernel.
//  1) k_probs: per (b,t) row softmax (one wave per row): 100 target
//     ratios -> fp16x2, PAIR-PACKED pk[b][t/2][word][2] (word w = labels
//     2w,2w+1; words 50..63 zero; element = t&1) + lb = log2(512*p_blank)
//     -> lbArr. Block 0 thread 0 zeroes out[].
//  2) k_ctc: 64 blocks x 128 threads: wave 0 = forward rows 0..511
//     (lane i = states 4i..4i+3), wave 1 = backward rows 1023..512
//     (lane j = states of ii=50-j; both use the verified wave_shr:1 DPP).
//     Pair loads (uint2), 8 register buffers, 7-chunk slack,
//     sched_barrier(0) after issue clauses. Per-lane power-of-2 rescale
//     every 8 steps, integer exponents + bit-built split factors.
//     Epilogue: bwd publishes states+exponent+lb via LDS, fwd combines
//     per-state in log2 domain -> wave logsumexp, atomicAdd(out, loss/64).

#define TT 1024
#define BB 64
#define KK 512
#define LL 100

static constexpr float L2E = 1.44269504088896340736f;
static constexpr float LN2 = 0.69314718055994530942f;

// lane i <- lane i-1, lane 0 <- 0  (DPP wave_shr:1, VALU pipe)
__device__ __forceinline__ float dpp_shr1_z(float x) {
  return __builtin_bit_cast(float,
      __builtin_amdgcn_update_dpp(0, __builtin_bit_cast(int, x),
                                  0x138, 0xf, 0xf, true));
}
__device__ __forceinline__ int dpp_shr1_zi(int x) {
  return __builtin_amdgcn_update_dpp(0, x, 0x138, 0xf, 0xf, true);
}

__device__ __forceinline__ float slog2(float x) {
  return x > 0.0f ? log2f(x) : -1.0e30f;
}

__device__ __forceinline__ float2 upk(unsigned u) {
  return __half22float2(__builtin_bit_cast(__half2, u));
}

__global__ __launch_bounds__(256) void k_probs(const float* __restrict__ logits,
                                               const int* __restrict__ targets,
                                               unsigned* __restrict__ pk,
                                               float* __restrict__ lbArr,
                                               float* __restrict__ out) {
  const int wid = threadIdx.x >> 6;
  const int lane = threadIdx.x & 63;
  const int row = (blockIdx.x << 2) + wid;      // row = b*T + t
  const int b = row >> 10;                      // T = 1024
  const float* x = logits + (size_t)row * KK;

  if (blockIdx.x == 0 && threadIdx.x == 0) out[0] = 0.0f;  // pre-k_ctc

  __shared__ float sx[4][KK];

  const float4 v0 = reinterpret_cast<const float4*>(x)[lane];
  const float4 v1 = reinterpret_cast<const float4*>(x)[lane + 64];
  float4* sp = reinterpret_cast<float4*>(sx[wid]);
  sp[lane] = v0;
  sp[lane + 64] = v1;

  float m = fmaxf(fmaxf(fmaxf(v0.x, v0.y), fmaxf(v0.z, v0.w)),
                  fmaxf(fmaxf(v1.x, v1.y), fmaxf(v1.z, v1.w)));
  #pragma unroll
  for (int d = 1; d < 64; d <<= 1) m = fmaxf(m, __shfl_xor(m, d));

  float e = exp2f((v0.x - m) * L2E) + exp2f((v0.y - m) * L2E) +
            exp2f((v0.z - m) * L2E) + exp2f((v0.w - m) * L2E) +
            exp2f((v1.x - m) * L2E) + exp2f((v1.y - m) * L2E) +
            exp2f((v1.z - m) * L2E) + exp2f((v1.w - m) * L2E);
  #pragma unroll
  for (int d = 1; d < 64; d <<= 1) e += __shfl_xor(e, d);

  __syncthreads();
  const float xb = sx[wid][0];                  // blank logit

  float ox = 0.0f, oy = 0.0f;
  if (lane >= 1 && lane <= 50) {
    const int2 c = *reinterpret_cast<const int2*>(
        targets + b * LL + (2 * lane - 2));
    ox = exp2f((sx[wid][c.x] - xb) * L2E);      // ratio p_lab / p_blank
    oy = exp2f((sx[wid][c.y] - xb) * L2E);
  }
  // word w holds labels 2w,2w+1; words 50..63 zero pads. pair element = t&1
  const int word = (lane == 0) ? 63 : (lane - 1);
  const __half2 h = __floats2half2_rn(ox, oy);
  pk[(size_t)(row >> 1) * 128 + word * 2 + (row & 1)] =
      __builtin_bit_cast(unsigned, h);

  // lb = log2(512 * p_blank) = (xb - m)*log2e + 9 - log2(sum exp)
  if (lane == 0) lbArr[row] = (xb - m) * L2E + 9.0f - log2f(e);
}

__global__ __launch_bounds__(128) void k_ctc(const unsigned* __restrict__ pk,
                                             const float* __restrict__ lbArr,
                                             const int* __restrict__ targets,
                                             float* __restrict__ out) {
  const int b = blockIdx.x;
  const int lane = threadIdx.x & 63;
  const int wv = threadIdx.x >> 6;              // 0 = forward, 1 = backward
  const int i = lane;
  const int* tg = targets + b * LL;

  __shared__ float sG[6][64];

  float S0 = 0.0f, S1 = 0.0f, S2 = 0.0f, S3 = 0.0f;
  int ea = 0;
  float f1 = 1.0f, f2 = 1.0f;

  // early-issue lb partial loads (independent of the recursion)
  const float4* lbv = reinterpret_cast<const float4*>(lbArr + (size_t)b * TT);
  const int lbbase = (wv == 0) ? 0 : 128;
  const float4 lb0 = lbv[lbbase + lane];
  const float4 lb1 = lbv[lbbase + lane + 64];

  // per-lane rescale: integer exponents, bit-constructed split factors
#define RESC()                                                             \
  do {                                                                     \
    const float m_ = fmaxf(fmaxf(S0, S1), fmaxf(S2, S3));                  \
    int E_ = (int)((__float_as_uint(m_) >> 23) & 255) - 127;               \
    E_ = (m_ > 0.0f) ? E_ : 0;                                             \
    const float sc_ = __uint_as_float((unsigned)(127 - E_) << 23);         \
    S0 *= sc_; S1 *= sc_; S2 *= sc_; S3 *= sc_;                            \
    ea += E_;                                                              \
    int dE_ = dpp_shr1_zi(ea) - ea;                                        \
    dE_ = dE_ < -250 ? -250 : (dE_ > 250 ? 250 : dE_);                     \
    const int h_ = dE_ / 2;                                                \
    f1 = __uint_as_float((unsigned)(127 + h_) << 23);                      \
    f2 = __uint_as_float((unsigned)(127 + (dE_ - h_)) << 23);              \
  } while (0)

  uint2 RA[8], RB[8], RC[8], RD[8], RE[8], RF[8], RG[8], RH[8];

  if (wv == 0) {
    // ---------- forward: rows 0..511, lane i = states 4i..4i+3 ----------
    const unsigned* gb = pk + (size_t)b * 512 * 128 + i * 2;  // word i
    float mA = 0.0f, mB = 0.0f;
    if (i > 0 && 2 * i <= LL - 1)
      mA = (tg[2 * i] != tg[2 * i - 1]) ? 1.0f : 0.0f;
    if (2 * i + 1 <= LL - 1)
      mB = (tg[2 * i + 1] != tg[2 * i]) ? 1.0f : 0.0f;
    S0 = (i == 0) ? 1.0f : 0.0f;                // virtual delta init

    // pair tp = CHN*8+j -> rows 2tp (.x) then 2tp+1 (.y)
#define FISSUE(BUF, CHN)                                                   \
    do {                                                                   \
      if ((CHN) < 32) {                                                    \
        _Pragma("unroll") for (int j = 0; j < 8; ++j)                      \
          BUF[j] = *reinterpret_cast<const uint2*>(                        \
              gb + (size_t)((CHN) * 8 + j) * 128);                         \
        __builtin_amdgcn_sched_barrier(0);                                 \
      }                                                                    \
    } while (0)
#define FSTEP(R)                                                           \
    do {                                                                   \
      const float A3 = dpp_shr1_z(S3) * f1 * f2;                           \
      const float n0 = S0 + A3;                                            \
      const float n1 = (S0 + S1 + mA * A3) * (R).x;                        \
      const float n2 = S1 + S2;                                            \
      const float n3 = (S2 + S3 + mB * S1) * (R).y;                        \
      S0 = n0; S1 = n1; S2 = n2; S3 = n3;                                  \
    } while (0)
#define FCOMPUTE(BUF)                                                      \
    do {                                                                   \
      _Pragma("unroll") for (int j = 0; j < 8; ++j) {                      \
        const float2 re = upk(BUF[j].x);                                   \
        FSTEP(re);                                                         \
        const float2 ro = upk(BUF[j].y);                                   \
        FSTEP(ro);                                                         \
        if ((j & 3) == 3) RESC();               /* every 8 steps */        \
      }                                                                    \
    } while (0)

    FISSUE(RA, 0); FISSUE(RB, 1); FISSUE(RC, 2); FISSUE(RD, 3);
    FISSUE(RE, 4); FISSUE(RF, 5); FISSUE(RG, 6);
    for (int c = 0; c < 32; c += 8) {
      FISSUE(RH, c + 7);  FCOMPUTE(RA);
      FISSUE(RA, c + 8);  FCOMPUTE(RB);
      FISSUE(RB, c + 9);  FCOMPUTE(RC);
      FISSUE(RC, c + 10); FCOMPUTE(RD);
      FISSUE(RD, c + 11); FCOMPUTE(RE);
      FISSUE(RE, c + 12); FCOMPUTE(RF);
      FISSUE(RF, c + 13); FCOMPUTE(RG);
      FISSUE(RG, c + 14); FCOMPUTE(RH);
    }
#undef FISSUE
#undef FSTEP
#undef FCOMPUTE
  } else {
    // ------- backward: rows 1023..512, lane j = states of ii = 50-j -----
    const int ii = 50 - i;
    const int w = (ii >= 0) ? ii : 50;          // word 50 = zeros (pad)
    const unsigned* gb = pk + (size_t)b * 512 * 128 + w * 2;
    float mBb = 0.0f, mAn = 0.0f;
    if (ii >= 0 && 2 * ii + 1 <= LL - 1)
      mBb = (tg[2 * ii + 1] != tg[2 * ii]) ? 1.0f : 0.0f;
    if (ii >= 0 && ii <= 48)
      mAn = (tg[2 * ii + 2] != tg[2 * ii + 1]) ? 1.0f : 0.0f;
    if (i == 0) S0 = 1.0f;                      // state 200 (ii = 50)
    if (i == 1) S3 = 1.0f;                      // state 199 (ii = 49)

    // pair tp = 511-(CHN*8+j) -> rows 2tp+1 (.y) then 2tp (.x), descending
#define BISSUE(BUF, CHN)                                                   \
    do {                                                                   \
      if ((CHN) < 32) {                                                    \
        _Pragma("unroll") for (int j = 0; j < 8; ++j)                      \
          BUF[j] = *reinterpret_cast<const uint2*>(                        \
              gb + (size_t)(511 - ((CHN) * 8 + j)) * 128);                 \
        __builtin_amdgcn_sched_barrier(0);                                 \
      }                                                                    \
    } while (0)
#define BSTEP(R)                                                           \
    do {                                                                   \
      const float s2 = dpp_shr1_z((R).x);       /* label 2ii+2 ratio */    \
      const float H0 = dpp_shr1_z(S0) * f1 * f2;                           \
      const float H1 = dpp_shr1_z(S1) * f1 * f2;                           \
      const float u = (R).x * S1;                                          \
      const float v = (R).y * S3;                                          \
      const float n0 = S0 + u;                                             \
      const float n1 = u + fmaf(mBb, v, S2);                               \
      const float n2 = S2 + v;                                             \
      const float n3 = v + fmaf(mAn, s2 * H1, H0);                         \
      S0 = n0; S1 = n1; S2 = n2; S3 = n3;                                  \
    } while (0)
#define BCOMPUTE(BUF)                                                      \
    do {                                                                   \
      _Pragma("unroll") for (int j = 0; j < 8; ++j) {                      \
        const float2 ro = upk(BUF[j].y);                                   \
        BSTEP(ro);                                                         \
        const float2 re = upk(BUF[j].x);                                   \
        BSTEP(re);                                                         \
        if ((j & 3) == 3) RESC();               /* every 8 steps */        \
      }                                                                    \
    } while (0)

    BISSUE(RA, 0); BISSUE(RB, 1); BISSUE(RC, 2); BISSUE(RD, 3);
    BISSUE(RE, 4); BISSUE(RF, 5); BISSUE(RG, 6);
    for (int c = 0; c < 32; c += 8) {
      BISSUE(RH, c + 7);  BCOMPUTE(RA);
      BISSUE(RA, c + 8);  BCOMPUTE(RB);
      BISSUE(RB, c + 9);  BCOMPUTE(RC);
      BISSUE(RC, c + 10); BCOMPUTE(RD);
      BISSUE(RD, c + 11); BCOMPUTE(RE);
      BISSUE(RE, c + 12); BCOMPUTE(RF);
      BISSUE(RF, c + 13); BCOMPUTE(RG);
      BISSUE(RG, c + 14); BCOMPUTE(RH);
    }
#undef BISSUE
#undef BSTEP
#undef BCOMPUTE
  }
#undef RESC

  // lb partial reduce (loads were issued before the main loop)
  float s4 = (lb0.x + lb0.y) + (lb0.z + lb0.w) +
             (lb1.x + lb1.y) + (lb1.z + lb1.w);
  #pragma unroll
  for (int d = 1; d < 64; d <<= 1) s4 += __shfl_xor(s4, d);

  if (wv == 1) {
    sG[0][lane] = S0; sG[1][lane] = S1; sG[2][lane] = S2; sG[3][lane] = S3;
    sG[4][lane] = (float)ea;
    if (lane == 0) sG[5][0] = s4;
  }

  __syncthreads();                              // backward publishes sG

  if (wv == 0) {
    const int gj = (i <= 50) ? (50 - i) : 63;   // bwd lane w/ states 4i..
    const float eb = sG[4][gj];
    const float eff = (float)ea;
    float w0 = slog2(S0) + eff + slog2(sG[0][gj]) + eb;
    float w1 = slog2(S1) + eff + slog2(sG[1][gj]) + eb;
    float w2 = slog2(S2) + eff + slog2(sG[2][gj]) + eb;
    float w3 = slog2(S3) + eff + slog2(sG[3][gj]) + eb;
    float wm = fmaxf(fmaxf(w0, w1), fmaxf(w2, w3));
    #pragma unroll
    for (int d = 1; d < 64; d <<= 1) wm = fmaxf(wm, __shfl_xor(wm, d));
    float ss = exp2f(w0 - wm) + exp2f(w1 - wm) +
               exp2f(w2 - wm) + exp2f(w3 - wm);
    #pragma unroll
    for (int d = 1; d < 64; d <<= 1) ss += __shfl_xor(ss, d);

    if (i == 0) {
      const float lbsum = s4 + sG[5][0];        // fwd + bwd halves
      float loss = 0.0f;                        // zero_infinity
      if (wm > -1.0e29f) {
        const float logl2 = wm + log2f(ss) + lbsum - (float)(TT * 9);
        loss = -(logl2 * LN2) / (float)LL;
      }
      atomicAdd(out, loss * (1.0f / (float)BB));
    }
  }
}

extern "C" void kernel_launch(void* const* d_in, const int* in_sizes, int n_in,
                              void* d_out, int out_size, void* d_ws, size_t ws_size,
                              hipStream_t stream) {
  const float* logits = (const float*)d_in[0];   // (64, 1024, 512) f32
  const int* targets = (const int*)d_in[1];      // (64, 100) i32
  float* out = (float*)d_out;                    // scalar f32

  unsigned* pk = (unsigned*)d_ws;                // 64*512*128 u32 (16 MB)
  float* lbArr = (float*)d_ws + (size_t)BB * 512 * 128;  // 64*1024 f32

  hipLaunchKernelGGL(k_probs, dim3(BB * TT / 4), dim3(256), 0, stream,
                     logits, targets, pk, lbArr, out);
  hipLaunchKernelGGL(k_ctc, dim3(BB), dim3(128), 0, stream,
                     pk, lbArr, targets, out);
}